// Round 15
// baseline (209.984 us; speedup 1.0000x reference)
//
#include <hip/hip_runtime.h>

// Problem constants
#define B_   4
#define C_   256
#define L_   4096     // H*W = 64*64
#define NH_  4
#define D_   64       // head dim
#define G_   32       // groups
#define CPG_ 8        // channels per group

typedef __bf16 bf16x8 __attribute__((ext_vector_type(8)));
typedef float  f32x4  __attribute__((ext_vector_type(4)));

__device__ __forceinline__ ushort f2bf(float f) {
  union { float f; unsigned u; } c; c.f = f;
  unsigned u = c.u;
  return (ushort)((u + 0x7fffu + ((u >> 16) & 1u)) >> 16);   // RNE, finite values only
}
__device__ __forceinline__ float bf2f(ushort h) {
  union { unsigned u; float f; } c; c.u = ((unsigned)h) << 16; return c.f;
}
__device__ __forceinline__ unsigned fbits(float f) {
  union { float f; unsigned u; } c; c.f = f; return c.u;
}
__device__ __forceinline__ float fastexp2(float x) {
#if __has_builtin(__builtin_amdgcn_exp2f)
  return __builtin_amdgcn_exp2f(x);
#else
  return exp2f(x);
#endif
}

// ---------------------------------------------------------------------------
// 0) pre_kernel = GN stats (float4 loads) + weight cvt (R14-proven).
//    blocks [0,512): stats, bg(128) x chunk(4), chunk covers 1024 l.
//    blocks [512,768): cvt (f32->bf16 of qkv_w / proj_w).
//    R13 lesson: cooperative grid.sync costs ~60us/sync -> 4-dispatch floor.
// ---------------------------------------------------------------------------
__global__ __launch_bounds__(256) void pre_kernel(const float* __restrict__ x,
                                                  const float* __restrict__ wqf,
                                                  const float* __restrict__ wpf,
                                                  ushort* __restrict__ wq,
                                                  ushort* __restrict__ wp,
                                                  float* __restrict__ stats2) {
  int bidx = blockIdx.x;
  int tid  = threadIdx.x;
  if (bidx >= 512) {
    int t = (bidx - 512) * 256 + tid;         // 65536 threads, 4 elems each
    const int NQ4 = (768 * 256) / 4;          // 49152
    float4 v;
    if (t < NQ4) {
      v = ((const float4*)wqf)[t];
      ((ushort4*)wq)[t] = make_ushort4(f2bf(v.x), f2bf(v.y), f2bf(v.z), f2bf(v.w));
    } else {
      int i = t - NQ4;
      v = ((const float4*)wpf)[i];
      ((ushort4*)wp)[i] = make_ushort4(f2bf(v.x), f2bf(v.y), f2bf(v.z), f2bf(v.w));
    }
    return;
  }
  // GN stats part: bidx = bg*4 + chunk (chunk = 1024 l)
  int bg = bidx >> 2, chunk = bidx & 3;
  int b = bg >> 5, g = bg & 31;
  const float* xg = x + ((size_t)b * C_ + g * CPG_) * L_ + chunk * 1024;

  float s = 0.f, ss = 0.f;
  for (int c = 0; c < CPG_; ++c) {
    float4 v = ((const float4*)(xg + (size_t)c * L_))[tid];
    s  += (v.x + v.y) + (v.z + v.w);
    ss += (v.x * v.x + v.y * v.y) + (v.z * v.z + v.w * v.w);
  }
  for (int off = 32; off; off >>= 1) { s += __shfl_xor(s, off); ss += __shfl_xor(ss, off); }
  __shared__ float red[8];
  int w = tid >> 6;
  if ((tid & 63) == 0) { red[w] = s; red[4 + w] = ss; }
  __syncthreads();
  if (tid == 0) {
    stats2[bidx * 2]     = red[0] + red[1] + red[2] + red[3];
    stats2[bidx * 2 + 1] = red[4] + red[5] + red[6] + red[7];
  }
}

// ---------------------------------------------------------------------------
// 2) QKV GEMM v3: GN-apply fused, 1024 blocks x 16 l-rows (was 512 x 32).
//    R14's 512-block config ran at 2 blocks/CU with 32 scalar 4B x-loads
//    per thread in Phase A -- latency-bound with no TLP.  v3: per-thread
//    loads halve (16), LDS drops to 8.4KB, grid 1024 -> 4 blocks/CU
//    (16 waves/CU) for 2x TLP.  Phase B: 1 B-frag (16 rows), acc[4];
//    MFMA-per-output, x traffic, store coalescing unchanged.  w re-reads
//    double but are L2-resident.
//    q,k (b,h,L,d); v (b,h,d,L).  q PRE-SCALED by 0.125*log2(e).
// ---------------------------------------------------------------------------
__global__ __launch_bounds__(256) void qkv_kernel(const float* __restrict__ x,
                                                  const float* __restrict__ stats2,
                                                  const float* __restrict__ gw,
                                                  const float* __restrict__ gb,
                                                  const ushort* __restrict__ w,
                                                  const float* __restrict__ bias,
                                                  ushort* __restrict__ q,
                                                  ushort* __restrict__ k,
                                                  ushort* __restrict__ v) {
  __shared__ __align__(16) ushort h_lds[16][264];   // 16 l x 256 c, +8 pad

  int tid  = threadIdx.x;
  int wv_  = tid >> 6, lane = tid & 63;
  int quad = lane >> 4, col = lane & 15;
  int bid  = (int)blockIdx.x;
  int b    = bid >> 8;                     // 4
  int lt   = bid & 255;                    // 256 l-tiles of 16
  int l0   = lt * 16;

  // ---- Phase A: GN-normalize 16 rows x 256 ch into LDS ----
  {
    int ll = tid & 15, chunk = tid >> 4;   // chunk 0..15 -> 16 channels
    int c0 = chunk * 16;
    const float inv_n = 1.0f / (CPG_ * L_);
    float mean[2], rstd[2];
#pragma unroll
    for (int gg = 0; gg < 2; ++gg) {
      int bg = b * 32 + chunk * 2 + gg;
      float s = 0.f, ss = 0.f;
#pragma unroll
      for (int c2 = 0; c2 < 4; ++c2) {
        s  += stats2[(bg * 4 + c2) * 2];
        ss += stats2[(bg * 4 + c2) * 2 + 1];
      }
      mean[gg] = s * inv_n;
      float var = ss * inv_n - mean[gg] * mean[gg];
      rstd[gg] = rsqrtf(var + 1e-5f);
    }
    int l = l0 + ll;
    union { uint4 u[2]; ushort s[16]; } o;
#pragma unroll
    for (int c = 0; c < 16; ++c) {
      int gg = c >> 3;
      float wvv = gw[c0 + c], bvv = gb[c0 + c];
      float val = x[((size_t)b * C_ + c0 + c) * L_ + l];
      o.s[c] = f2bf((val - mean[gg]) * rstd[gg] * wvv + bvv);
    }
#pragma unroll
    for (int i = 0; i < 2; ++i)
      *(uint4*)&h_lds[ll][c0 + i * 8] = o.u[i];
  }
  __syncthreads();

  // ---- Phase B: 3 GEMM passes per wave (ot = wv_ + 4p), 1 B-frag ----
#pragma unroll
  for (int p = 0; p < 3; ++p) {
    int ot = wv_ + 4 * p;                   // 0..11
    int o0 = ot * 64;
    const ushort* abase = w + (size_t)(o0 + col) * C_ + quad * 8;

    f32x4 acc[4];
    for (int i = 0; i < 4; ++i) acc[i] = (f32x4){0.f, 0.f, 0.f, 0.f};

#pragma unroll
    for (int k0 = 0; k0 < C_; k0 += 32) {
      bf16x8 a[4];
#pragma unroll
      for (int i = 0; i < 4; ++i) a[i] = *(const bf16x8*)(abase + (size_t)(i * 16) * C_ + k0);
      bf16x8 bb = *(const bf16x8*)&h_lds[col][k0 + quad * 8];
#pragma unroll
      for (int i = 0; i < 4; ++i)
        acc[i] = __builtin_amdgcn_mfma_f32_16x16x32_bf16(a[i], bb, acc[i], 0, 0, 0);
    }

    int third = o0 >> 8;                       // wave-uniform (o0 is 64-aligned)
    int hh    = (o0 & 255) >> 6;               // wave-uniform
    float scale = (third == 0) ? 0.180336880111120f : 1.0f;  // 0.125*log2(e) on q
    int l = l0 + col;
#pragma unroll
    for (int i = 0; i < 4; ++i) {
      int oo = o0 + i * 16 + quad * 4;
      int dd = i * 16 + quad * 4;
      ushort pk[4];
      for (int r = 0; r < 4; ++r) pk[r] = f2bf((acc[i][r] + bias[oo + r]) * scale);
      if (third < 2) {
        ushort* dst = (third ? k : q) + (((size_t)(b * NH_ + hh) * L_ + l) * D_ + dd);
        *(ushort4*)dst = make_ushort4(pk[0], pk[1], pk[2], pk[3]);
      } else {
        for (int r = 0; r < 4; ++r)
          v[((size_t)(b * NH_ + hh) * D_ + dd + r) * L_ + l] = pk[r];
      }
    }
  }
}

// ---------------------------------------------------------------------------
// 3) Flash attention (MFMA) — R8/R12 configuration (73.5us proven):
//    split-2, grid 512, 256 thr, 64 q-rows/wave, V/K LDS dbuf + kpos
//    permutation, MFMA-psum (ones trick), one barrier/tile, setprio on the
//    pure-MFMA QK cluster.
// ---------------------------------------------------------------------------
__global__ __launch_bounds__(256, 2) void attn_kernel(const ushort* __restrict__ q,
                                                      const ushort* __restrict__ k,
                                                      const ushort* __restrict__ v,
                                                      ushort* __restrict__ p0,
                                                      ushort* __restrict__ p1,
                                                      float* __restrict__ psumbuf) {
  __shared__ __align__(16) ushort k_lds[2][64][72];   // K tiles, +8 pad
  __shared__ __align__(16) ushort v_lds[2][64][72];   // V^T tiles (permuted), +8 pad

  int tid   = threadIdx.x;
  int w     = tid >> 6, lane = tid & 63;
  int quad  = lane >> 4, col = lane & 15;
  int bid   = (int)blockIdx.x;
  bid = (bid & 7) * 64 + (bid >> 3);     // XCD-contiguous work ids (512 % 8 == 0)
  int split = bid >> 8;                  // 0 or 1
  int bh    = (bid >> 4) & 15;
  int qblk  = bid & 15;

  const ushort* qp = q + (size_t)bh * L_ * D_;
  const ushort* kp = k + (size_t)bh * L_ * D_;
  const ushort* vp = v + (size_t)bh * D_ * L_;

  int qrow0 = qblk * 256 + w * 64;       // this wave's 64 q-rows
  bf16x8 bq[4][2];                       // [frag][c]
#pragma unroll
  for (int f = 0; f < 4; ++f)
#pragma unroll
    for (int c = 0; c < 2; ++c)
      bq[f][c] = *(const bf16x8*)(qp + (size_t)(qrow0 + f * 16 + col) * D_ + c * 32 + quad * 8);

  f32x4 oacc[4][4];
#pragma unroll
  for (int f = 0; f < 4; ++f)
    for (int t = 0; t < 4; ++t) oacc[f][t] = (f32x4){0.f, 0.f, 0.f, 0.f};
  f32x4 pacc[4];
#pragma unroll
  for (int f = 0; f < 4; ++f) pacc[f] = (f32x4){0.f, 0.f, 0.f, 0.f};
  const f32x4 Z = (f32x4){0.f, 0.f, 0.f, 0.f};

  union { ushort s[8]; bf16x8 v8; } one_u;
#pragma unroll
  for (int i = 0; i < 8; ++i) one_u.s[i] = 0x3F80;    // bf16 1.0
  bf16x8 ones = one_u.v8;

  int vrow = tid >> 2, vchunk = tid & 3;
  int vwoff = (vchunk >> 1) * 32 + (vchunk & 1) * 4;   // permuted V store base
  int kt0 = split * (L_ / 2), kt_end = kt0 + L_ / 2;

  // prologue: stage tile kt0 into buffer 0 (V permuted)
  {
    const uint4* ksrc = (const uint4*)(kp + (size_t)kt0 * D_);   // 8 KB contiguous
    uint4 a  = ksrc[tid];
    uint4 b2 = ksrc[tid + 256];
    const uint4* vsrc = (const uint4*)(vp + (size_t)vrow * L_ + kt0);
    uint4 c0 = vsrc[vchunk * 2];
    uint4 c1 = vsrc[vchunk * 2 + 1];
    *(uint4*)&k_lds[0][tid >> 3][(tid & 7) * 8] = a;
    *(uint4*)&k_lds[0][32 + (tid >> 3)][(tid & 7) * 8] = b2;
    ushort* vb = &v_lds[0][vrow][vwoff];
    *(uint2*)(vb + 0)  = make_uint2(c0.x, c0.y);
    *(uint2*)(vb + 8)  = make_uint2(c0.z, c0.w);
    *(uint2*)(vb + 16) = make_uint2(c1.x, c1.y);
    *(uint2*)(vb + 24) = make_uint2(c1.z, c1.w);
  }
  __syncthreads();

  int cur = 0;
  for (int kt = kt0; kt < kt_end; kt += 64) {
    bool has_next = (kt + 64) < kt_end;   // block-uniform

    // ---- Phase 1: QK^T for BOTH 32-kpos halves (32 indep MFMAs) ----
    f32x4 s[2][4][2];   // [h][f][{rows col, rows 16+col}]
    __builtin_amdgcn_s_setprio(1);
#pragma unroll
    for (int h = 0; h < 2; ++h) {
      bf16x8 a00 = *(const bf16x8*)&k_lds[cur][h * 32 + col][quad * 8];
      bf16x8 a01 = *(const bf16x8*)&k_lds[cur][h * 32 + col][32 + quad * 8];
      bf16x8 a10 = *(const bf16x8*)&k_lds[cur][h * 32 + 16 + col][quad * 8];
      bf16x8 a11 = *(const bf16x8*)&k_lds[cur][h * 32 + 16 + col][32 + quad * 8];
#pragma unroll
      for (int f = 0; f < 4; ++f) {
        s[h][f][0] = __builtin_amdgcn_mfma_f32_16x16x32_bf16(a00, bq[f][0], Z, 0, 0, 0);
        s[h][f][1] = __builtin_amdgcn_mfma_f32_16x16x32_bf16(a10, bq[f][0], Z, 0, 0, 0);
        s[h][f][0] = __builtin_amdgcn_mfma_f32_16x16x32_bf16(a01, bq[f][1], s[h][f][0], 0, 0, 0);
        s[h][f][1] = __builtin_amdgcn_mfma_f32_16x16x32_bf16(a11, bq[f][1], s[h][f][1], 0, 0, 0);
      }
    }
    __builtin_amdgcn_s_setprio(0);

    // ---- Phase 2: issue next tile's global loads (land under exp/PV) ----
    uint4 nk0, nk1, nv0, nv1;
    if (has_next) {
      const uint4* ksrc = (const uint4*)(kp + (size_t)(kt + 64) * D_);
      nk0 = ksrc[tid];
      nk1 = ksrc[tid + 256];
      const uint4* vsrc = (const uint4*)(vp + (size_t)vrow * L_ + (kt + 64));
      nv0 = vsrc[vchunk * 2];
      nv1 = vsrc[vchunk * 2 + 1];
    }

    // ---- Phase 3: per half: exp/pack (VALU) + psum (MFMA) + PV (MFMA) ----
#pragma unroll
    for (int h = 0; h < 2; ++h) {
      bf16x8 pb[4];
#pragma unroll
      for (int f = 0; f < 4; ++f) {
        float pe0[4], pe1[4];
#pragma unroll
        for (int r = 0; r < 4; ++r) {
          pe0[r] = fastexp2(s[h][f][0][r]);
          pe1[r] = fastexp2(s[h][f][1][r]);
        }
        // B-frag IS our own values under the kpos permutation.
        union { unsigned u[4]; bf16x8 v8; } pc;
        pc.u[0] = __builtin_amdgcn_perm(fbits(pe0[1]), fbits(pe0[0]), 0x07060302u);
        pc.u[1] = __builtin_amdgcn_perm(fbits(pe0[3]), fbits(pe0[2]), 0x07060302u);
        pc.u[2] = __builtin_amdgcn_perm(fbits(pe1[1]), fbits(pe1[0]), 0x07060302u);
        pc.u[3] = __builtin_amdgcn_perm(fbits(pe1[3]), fbits(pe1[2]), 0x07060302u);
        pb[f] = pc.v8;
      }
      // psum on the matrix pipe: row-sum of P (permutation-invariant)
#pragma unroll
      for (int f = 0; f < 4; ++f)
        pacc[f] = __builtin_amdgcn_mfma_f32_16x16x32_bf16(ones, pb[f], pacc[f], 0, 0, 0);
#pragma unroll
      for (int t = 0; t < 4; ++t) {
        // ONE b128 read feeds FOUR MFMAs (V pre-permuted at store time)
        bf16x8 av = *(const bf16x8*)&v_lds[cur][t * 16 + col][h * 32 + quad * 8];
#pragma unroll
        for (int f = 0; f < 4; ++f)
          oacc[f][t] = __builtin_amdgcn_mfma_f32_16x16x32_bf16(av, pb[f], oacc[f][t], 0, 0, 0);
      }
    }

    if (has_next) {
      int nb = cur ^ 1;
      *(uint4*)&k_lds[nb][tid >> 3][(tid & 7) * 8] = nk0;
      *(uint4*)&k_lds[nb][32 + (tid >> 3)][(tid & 7) * 8] = nk1;
      ushort* vb = &v_lds[nb][vrow][vwoff];
      *(uint2*)(vb + 0)  = make_uint2(nv0.x, nv0.y);
      *(uint2*)(vb + 8)  = make_uint2(nv0.z, nv0.w);
      *(uint2*)(vb + 16) = make_uint2(nv1.x, nv1.y);
      *(uint2*)(vb + 24) = make_uint2(nv1.z, nv1.w);
      __syncthreads();
      cur = nb;
    }
  }

  ushort* po = split ? p1 : p0;
#pragma unroll
  for (int f = 0; f < 4; ++f) {
    for (int t = 0; t < 4; ++t) {
      ushort ok[4];
      for (int r = 0; r < 4; ++r) ok[r] = f2bf(oacc[f][t][r]);   // unnormalized
      ushort* dst = po + ((size_t)bh * L_ + qrow0 + f * 16 + col) * D_ + t * 16 + quad * 4;
      *(ushort4*)dst = make_ushort4(ok[0], ok[1], ok[2], ok[3]);
    }
    if (quad == 0)
      psumbuf[split * (16 * L_) + bh * L_ + qrow0 + f * 16 + col] = pacc[f][0];
  }
}

// ---------------------------------------------------------------------------
// 3b) Combine (FALLBACK path only): oat = (U0+U1)/(P0+P1), in-place over p0.
// ---------------------------------------------------------------------------
__global__ __launch_bounds__(256) void comb_kernel(ushort* __restrict__ p0,      // in/out (oat)
                                                   const ushort* __restrict__ p1,
                                                   const float* __restrict__ ps) {
  int idx = blockIdx.x * 256 + threadIdx.x;    // 524,288 uint4s = 16*4096*64 bf16
  int row = idx >> 3;                          // bh*4096 + qrow (8 elems/row-chunk)
  float inv = 1.0f / (ps[row] + ps[16 * L_ + row]);
  union { uint4 u; ushort s[8]; } ua, ub, o;
  ua.u = ((const uint4*)p0)[idx];
  ub.u = ((const uint4*)p1)[idx];
#pragma unroll
  for (int e = 0; e < 8; ++e)
    o.s[e] = f2bf((bf2f(ua.s[e]) + bf2f(ub.s[e])) * inv);
  ((uint4*)p0)[idx] = o.u;
}

// ---------------------------------------------------------------------------
// 4) Proj GEMM + residual (MFMA), per-block LDS combine (R11/R12-proven).
//    FUSED=true: stage combined A-tile once per block; FUSED=false: classic.
// ---------------------------------------------------------------------------
template<bool FUSED>
__global__ __launch_bounds__(256) void proj_kernel(const ushort* __restrict__ p0,
                                                   const ushort* __restrict__ p1,
                                                   const float* __restrict__ ps,
                                                   const ushort* __restrict__ pw,
                                                   const float* __restrict__ pb,
                                                   const float* __restrict__ x,
                                                   float* __restrict__ out) {
  __shared__ __align__(16) ushort a_lds[32][264];   // 32 l x 256 ch, +8 pad

  int tid  = threadIdx.x;
  int w    = tid >> 6, lane = tid & 63;
  int quad = lane >> 4, col = lane & 15;
  int bid  = (int)blockIdx.x;                 // 1024 blocks
  int oct  = (bid & 1) * 4 + w;               // 8 oc-tiles of 32
  int lt   = (bid >> 1) & 127;                // 128 l-tiles of 32
  int b    = bid >> 8;
  int l0 = lt * 32, oc0 = oct * 32;

  if (FUSED) {
    // stage combined A-tile: thread -> (l_local = tid&31, chunk = tid>>5)
    int ll = tid & 31, chunk = tid >> 5;      // chunk 0..7 -> 32 channels
    int hh = chunk >> 1, d0 = (chunk & 1) * 32;
    size_t row = (size_t)(b * NH_ + hh) * L_ + l0 + ll;
    float inv = 1.0f / (ps[row] + ps[16 * L_ + row]);
    const uint4* s0 = (const uint4*)(p0 + row * D_ + d0);
    const uint4* s1 = (const uint4*)(p1 + row * D_ + d0);
    union { uint4 u[4]; ushort s[32]; } ua, ub, o;
#pragma unroll
    for (int i = 0; i < 4; ++i) { ua.u[i] = s0[i]; ub.u[i] = s1[i]; }
#pragma unroll
    for (int e = 0; e < 32; ++e)
      o.s[e] = f2bf((bf2f(ua.s[e]) + bf2f(ub.s[e])) * inv);
#pragma unroll
    for (int i = 0; i < 4; ++i)
      *(uint4*)&a_lds[ll][chunk * 32 + i * 8] = o.u[i];
    __syncthreads();
  }

  f32x4 acc[2][2];
  for (int i = 0; i < 2; ++i) for (int j = 0; j < 2; ++j)
    acc[i][j] = (f32x4){0.f, 0.f, 0.f, 0.f};

#pragma unroll
  for (int k0 = 0; k0 < C_; k0 += 32) {
    int hh = k0 >> 6, dk = k0 & 63;
    bf16x8 a[2], bb[2];
#pragma unroll
    for (int i = 0; i < 2; ++i) {
      if (FUSED) {
        a[i] = *(const bf16x8*)&a_lds[i * 16 + col][k0 + quad * 8];
      } else {
        a[i] = *(const bf16x8*)(p0 + ((size_t)(b * NH_ + hh) * L_ + l0 + i * 16 + col) * D_ + dk + quad * 8);
      }
    }
#pragma unroll
    for (int j = 0; j < 2; ++j)
      bb[j] = *(const bf16x8*)(pw + (size_t)(oc0 + j * 16 + col) * C_ + k0 + quad * 8);
#pragma unroll
    for (int i = 0; i < 2; ++i)
#pragma unroll
      for (int j = 0; j < 2; ++j)
        acc[i][j] = __builtin_amdgcn_mfma_f32_16x16x32_bf16(a[i], bb[j], acc[i][j], 0, 0, 0);
  }

#pragma unroll
  for (int j = 0; j < 2; ++j) {
    int oc = oc0 + j * 16 + col;
    float bias = pb[oc];
#pragma unroll
    for (int i = 0; i < 2; ++i) {
      int l = l0 + i * 16 + quad * 4;
      size_t off = ((size_t)b * C_ + oc) * L_ + l;
      float4 xv = *(const float4*)(x + off);
      float4 ov = make_float4(acc[i][j][0] + bias + xv.x,
                              acc[i][j][1] + bias + xv.y,
                              acc[i][j][2] + bias + xv.z,
                              acc[i][j][3] + bias + xv.w);
      *(float4*)(out + off) = ov;
    }
  }
}

// ---------------------------------------------------------------------------
extern "C" void kernel_launch(void* const* d_in, const int* in_sizes, int n_in,
                              void* d_out, int out_size, void* d_ws, size_t ws_size,
                              hipStream_t stream) {
  const float* x      = (const float*)d_in[0];
  const float* gn_w   = (const float*)d_in[1];
  const float* gn_b   = (const float*)d_in[2];
  const float* qkv_w  = (const float*)d_in[3];
  const float* qkv_b  = (const float*)d_in[4];
  const float* proj_w = (const float*)d_in[5];
  const float* proj_b = (const float*)d_in[6];
  float* out = (float*)d_out;     // OUTPUT IS F32

  const size_t TEN = (size_t)B_ * C_ * L_;   // 4,194,304 elements
  // ws base layout (34.1 MB): q | k | v | oat | wq | wp | [p1 | psum if room]
  // d_out (16.8 MB): st2 f32 4KB at +8.4MB (dead before out is written);
  //                  fallback also places p1/psum here.
  ushort* ws  = (ushort*)d_ws;
  ushort* q   = ws;                 // (B, nh, L, d) bf16 (pre-scaled)
  ushort* k   = ws + TEN;           // (B, nh, L, d) bf16
  ushort* v   = ws + 2 * TEN;       // (B, nh, d, L) bf16
  ushort* oat = ws + 3 * TEN;       // (B, nh, L, d) bf16 = partial-0
  ushort* wq  = ws + 4 * TEN;       // (768,256) bf16
  ushort* wp  = wq + 768 * 256;     // (256,256) bf16
  ushort* wend = wp + 256 * 256;    // end of base layout
  float*  st2 = (float*)((ushort*)d_out + TEN);  // 1024 f32 GN partials (pre-attn)

  const size_t base_bytes  = (size_t)(wend - ws) * 2;
  const size_t need_fused  = base_bytes + TEN * 2 /*p1*/ + (size_t)2 * 16 * L_ * 4 /*psum*/;
  const bool   fused       = ws_size >= need_fused;   // true on this harness (R9 evidence)

  pre_kernel <<<768,       256, 0, stream>>>(x, qkv_w, proj_w, wq, wp, st2);
  qkv_kernel <<<1024,      256, 0, stream>>>(x, st2, gn_w, gn_b, wq, qkv_b, q, k, v);

  if (fused) {
    ushort* p1w = wend;                    // partial-1 in ws
    float*  psw = (float*)(wend + TEN);    // psum[2][16][4096] in ws
    attn_kernel<<<512, 256, 0, stream>>>(q, k, v, oat, p1w, psw);
    proj_kernel<true><<<1024, 256, 0, stream>>>(oat, p1w, psw, wp, proj_b, x, out);
  } else {
    // fallback: p1 + psum live in d_out (st2 is dead after qkv)
    ushort* p1d = (ushort*)d_out + TEN;
    float*  psb = (float*)d_out;
    attn_kernel<<<512, 256, 0, stream>>>(q, k, v, oat, p1d, psb);
    comb_kernel<<<2048, 256, 0, stream>>>(oat, p1d, psb);
    proj_kernel<false><<<1024, 256, 0, stream>>>(oat, oat, psb, wp, proj_b, x, out);
  }
}

// Round 16
// 191.191 us; speedup vs baseline: 1.0983x; 1.0983x over previous
//
#include <hip/hip_runtime.h>

// Problem constants
#define B_   4
#define C_   256
#define L_   4096     // H*W = 64*64
#define NH_  4
#define D_   64       // head dim
#define G_   32       // groups
#define CPG_ 8        // channels per group

typedef __bf16 bf16x8 __attribute__((ext_vector_type(8)));
typedef float  f32x4  __attribute__((ext_vector_type(4)));

__device__ __forceinline__ ushort f2bf(float f) {
  union { float f; unsigned u; } c; c.f = f;
  unsigned u = c.u;
  return (ushort)((u + 0x7fffu + ((u >> 16) & 1u)) >> 16);   // RNE, finite values only
}
__device__ __forceinline__ float bf2f(ushort h) {
  union { unsigned u; float f; } c; c.u = ((unsigned)h) << 16; return c.f;
}
__device__ __forceinline__ unsigned fbits(float f) {
  union { float f; unsigned u; } c; c.f = f; return c.u;
}
__device__ __forceinline__ float fastexp2(float x) {
#if __has_builtin(__builtin_amdgcn_exp2f)
  return __builtin_amdgcn_exp2f(x);
#else
  return exp2f(x);
#endif
}

// ---------------------------------------------------------------------------
// 0) pre_kernel = GN stats (float4 loads) + weight cvt (R14-proven).
//    blocks [0,512): stats, bg(128) x chunk(4), chunk covers 1024 l.
//    blocks [512,768): cvt (f32->bf16 of qkv_w / proj_w).
//    R13 lesson: cooperative grid.sync costs ~60us/sync -> 4-dispatch floor.
// ---------------------------------------------------------------------------
__global__ __launch_bounds__(256) void pre_kernel(const float* __restrict__ x,
                                                  const float* __restrict__ wqf,
                                                  const float* __restrict__ wpf,
                                                  ushort* __restrict__ wq,
                                                  ushort* __restrict__ wp,
                                                  float* __restrict__ stats2) {
  int bidx = blockIdx.x;
  int tid  = threadIdx.x;
  if (bidx >= 512) {
    int t = (bidx - 512) * 256 + tid;         // 65536 threads, 4 elems each
    const int NQ4 = (768 * 256) / 4;          // 49152
    float4 v;
    if (t < NQ4) {
      v = ((const float4*)wqf)[t];
      ((ushort4*)wq)[t] = make_ushort4(f2bf(v.x), f2bf(v.y), f2bf(v.z), f2bf(v.w));
    } else {
      int i = t - NQ4;
      v = ((const float4*)wpf)[i];
      ((ushort4*)wp)[i] = make_ushort4(f2bf(v.x), f2bf(v.y), f2bf(v.z), f2bf(v.w));
    }
    return;
  }
  // GN stats part: bidx = bg*4 + chunk (chunk = 1024 l)
  int bg = bidx >> 2, chunk = bidx & 3;
  int b = bg >> 5, g = bg & 31;
  const float* xg = x + ((size_t)b * C_ + g * CPG_) * L_ + chunk * 1024;

  float s = 0.f, ss = 0.f;
  for (int c = 0; c < CPG_; ++c) {
    float4 v = ((const float4*)(xg + (size_t)c * L_))[tid];
    s  += (v.x + v.y) + (v.z + v.w);
    ss += (v.x * v.x + v.y * v.y) + (v.z * v.z + v.w * v.w);
  }
  for (int off = 32; off; off >>= 1) { s += __shfl_xor(s, off); ss += __shfl_xor(ss, off); }
  __shared__ float red[8];
  int w = tid >> 6;
  if ((tid & 63) == 0) { red[w] = s; red[4 + w] = ss; }
  __syncthreads();
  if (tid == 0) {
    stats2[bidx * 2]     = red[0] + red[1] + red[2] + red[3];
    stats2[bidx * 2 + 1] = red[4] + red[5] + red[6] + red[7];
  }
}

// ---------------------------------------------------------------------------
// 2) QKV GEMM v2 (R14-proven): GN-apply FUSED.  Grid 512 = b(4) x lt(128);
//    4 waves/block.  Phase A: GN-normalized 32-row x 256-ch tile from x into
//    LDS (thread: one l, 32 contiguous channels; lanes 0-31 read consecutive
//    l -> 128B-coalesced).  Phase B: 3 o-tile passes per wave, 2 B-frags
//    (32 l rows -> each w A-frag feeds 8 MFMAs).
//    R15 lesson: halving the l-tile halves w-operand reuse per MFMA ->
//    doubled L2 w-traffic, +19us.  Operand-reuse accounting first.
//    q,k (b,h,L,d); v (b,h,d,L).  q PRE-SCALED by 0.125*log2(e).
// ---------------------------------------------------------------------------
__global__ __launch_bounds__(256) void qkv_kernel(const float* __restrict__ x,
                                                  const float* __restrict__ stats2,
                                                  const float* __restrict__ gw,
                                                  const float* __restrict__ gb,
                                                  const ushort* __restrict__ w,
                                                  const float* __restrict__ bias,
                                                  ushort* __restrict__ q,
                                                  ushort* __restrict__ k,
                                                  ushort* __restrict__ v) {
  __shared__ __align__(16) ushort h_lds[32][264];   // 32 l x 256 c, +8 pad

  int tid  = threadIdx.x;
  int wv_  = tid >> 6, lane = tid & 63;
  int quad = lane >> 4, col = lane & 15;
  int bid  = (int)blockIdx.x;
  int b    = bid >> 7;
  int lt   = bid & 127;
  int l0   = lt * 32;

  // ---- Phase A: GN-normalize 32 rows x 256 ch into LDS ----
  {
    int ll = tid & 31, chunk = tid >> 5;    // chunk 0..7 -> 32 channels
    int c0 = chunk * 32;
    const float inv_n = 1.0f / (CPG_ * L_);
    float mean[4], rstd[4];
#pragma unroll
    for (int gg = 0; gg < 4; ++gg) {
      int bg = b * 32 + chunk * 4 + gg;
      float s = 0.f, ss = 0.f;
#pragma unroll
      for (int c2 = 0; c2 < 4; ++c2) {
        s  += stats2[(bg * 4 + c2) * 2];
        ss += stats2[(bg * 4 + c2) * 2 + 1];
      }
      mean[gg] = s * inv_n;
      float var = ss * inv_n - mean[gg] * mean[gg];
      rstd[gg] = rsqrtf(var + 1e-5f);
    }
    int l = l0 + ll;
    union { uint4 u[4]; ushort s[32]; } o;
#pragma unroll
    for (int c = 0; c < 32; ++c) {
      int gg = c >> 3;
      float wvv = gw[c0 + c], bvv = gb[c0 + c];
      float val = x[((size_t)b * C_ + c0 + c) * L_ + l];
      o.s[c] = f2bf((val - mean[gg]) * rstd[gg] * wvv + bvv);
    }
#pragma unroll
    for (int i = 0; i < 4; ++i)
      *(uint4*)&h_lds[ll][c0 + i * 8] = o.u[i];
  }
  __syncthreads();

  // ---- Phase B: 3 GEMM passes per wave (ot = wv_ + 4p) ----
#pragma unroll
  for (int p = 0; p < 3; ++p) {
    int ot = wv_ + 4 * p;                   // 0..11
    int o0 = ot * 64;
    const ushort* abase = w + (size_t)(o0 + col) * C_ + quad * 8;

    f32x4 acc[4][2];
    for (int i = 0; i < 4; ++i) for (int j = 0; j < 2; ++j)
      acc[i][j] = (f32x4){0.f, 0.f, 0.f, 0.f};

#pragma unroll
    for (int k0 = 0; k0 < C_; k0 += 32) {
      bf16x8 a[4], bb[2];
#pragma unroll
      for (int i = 0; i < 4; ++i) a[i]  = *(const bf16x8*)(abase + (size_t)(i * 16) * C_ + k0);
#pragma unroll
      for (int j = 0; j < 2; ++j) bb[j] = *(const bf16x8*)&h_lds[j * 16 + col][k0 + quad * 8];
#pragma unroll
      for (int i = 0; i < 4; ++i)
#pragma unroll
        for (int j = 0; j < 2; ++j)
          acc[i][j] = __builtin_amdgcn_mfma_f32_16x16x32_bf16(a[i], bb[j], acc[i][j], 0, 0, 0);
    }

    int third = o0 >> 8;                       // wave-uniform (o0 is 64-aligned)
    int hh    = (o0 & 255) >> 6;               // wave-uniform
    float scale = (third == 0) ? 0.180336880111120f : 1.0f;  // 0.125*log2(e) on q
#pragma unroll
    for (int i = 0; i < 4; ++i) {
      int oo = o0 + i * 16 + quad * 4;
      int dd = i * 16 + quad * 4;
#pragma unroll
      for (int j = 0; j < 2; ++j) {
        int l = l0 + j * 16 + col;
        ushort pk[4];
        for (int r = 0; r < 4; ++r) pk[r] = f2bf((acc[i][j][r] + bias[oo + r]) * scale);
        if (third < 2) {
          ushort* dst = (third ? k : q) + (((size_t)(b * NH_ + hh) * L_ + l) * D_ + dd);
          *(ushort4*)dst = make_ushort4(pk[0], pk[1], pk[2], pk[3]);
        } else {
          for (int r = 0; r < 4; ++r)
            v[((size_t)(b * NH_ + hh) * D_ + dd + r) * L_ + l] = pk[r];
        }
      }
    }
  }
}

// ---------------------------------------------------------------------------
// 3) Flash attention (MFMA) — R8/R12 configuration (73.5us proven):
//    split-2, grid 512, 256 thr, 64 q-rows/wave, V/K LDS dbuf + kpos
//    permutation, MFMA-psum (ones trick), one barrier/tile, setprio on the
//    pure-MFMA QK cluster.
// ---------------------------------------------------------------------------
__global__ __launch_bounds__(256, 2) void attn_kernel(const ushort* __restrict__ q,
                                                      const ushort* __restrict__ k,
                                                      const ushort* __restrict__ v,
                                                      ushort* __restrict__ p0,
                                                      ushort* __restrict__ p1,
                                                      float* __restrict__ psumbuf) {
  __shared__ __align__(16) ushort k_lds[2][64][72];   // K tiles, +8 pad
  __shared__ __align__(16) ushort v_lds[2][64][72];   // V^T tiles (permuted), +8 pad

  int tid   = threadIdx.x;
  int w     = tid >> 6, lane = tid & 63;
  int quad  = lane >> 4, col = lane & 15;
  int bid   = (int)blockIdx.x;
  bid = (bid & 7) * 64 + (bid >> 3);     // XCD-contiguous work ids (512 % 8 == 0)
  int split = bid >> 8;                  // 0 or 1
  int bh    = (bid >> 4) & 15;
  int qblk  = bid & 15;

  const ushort* qp = q + (size_t)bh * L_ * D_;
  const ushort* kp = k + (size_t)bh * L_ * D_;
  const ushort* vp = v + (size_t)bh * D_ * L_;

  int qrow0 = qblk * 256 + w * 64;       // this wave's 64 q-rows
  bf16x8 bq[4][2];                       // [frag][c]
#pragma unroll
  for (int f = 0; f < 4; ++f)
#pragma unroll
    for (int c = 0; c < 2; ++c)
      bq[f][c] = *(const bf16x8*)(qp + (size_t)(qrow0 + f * 16 + col) * D_ + c * 32 + quad * 8);

  f32x4 oacc[4][4];
#pragma unroll
  for (int f = 0; f < 4; ++f)
    for (int t = 0; t < 4; ++t) oacc[f][t] = (f32x4){0.f, 0.f, 0.f, 0.f};
  f32x4 pacc[4];
#pragma unroll
  for (int f = 0; f < 4; ++f) pacc[f] = (f32x4){0.f, 0.f, 0.f, 0.f};
  const f32x4 Z = (f32x4){0.f, 0.f, 0.f, 0.f};

  union { ushort s[8]; bf16x8 v8; } one_u;
#pragma unroll
  for (int i = 0; i < 8; ++i) one_u.s[i] = 0x3F80;    // bf16 1.0
  bf16x8 ones = one_u.v8;

  int vrow = tid >> 2, vchunk = tid & 3;
  int vwoff = (vchunk >> 1) * 32 + (vchunk & 1) * 4;   // permuted V store base
  int kt0 = split * (L_ / 2), kt_end = kt0 + L_ / 2;

  // prologue: stage tile kt0 into buffer 0 (V permuted)
  {
    const uint4* ksrc = (const uint4*)(kp + (size_t)kt0 * D_);   // 8 KB contiguous
    uint4 a  = ksrc[tid];
    uint4 b2 = ksrc[tid + 256];
    const uint4* vsrc = (const uint4*)(vp + (size_t)vrow * L_ + kt0);
    uint4 c0 = vsrc[vchunk * 2];
    uint4 c1 = vsrc[vchunk * 2 + 1];
    *(uint4*)&k_lds[0][tid >> 3][(tid & 7) * 8] = a;
    *(uint4*)&k_lds[0][32 + (tid >> 3)][(tid & 7) * 8] = b2;
    ushort* vb = &v_lds[0][vrow][vwoff];
    *(uint2*)(vb + 0)  = make_uint2(c0.x, c0.y);
    *(uint2*)(vb + 8)  = make_uint2(c0.z, c0.w);
    *(uint2*)(vb + 16) = make_uint2(c1.x, c1.y);
    *(uint2*)(vb + 24) = make_uint2(c1.z, c1.w);
  }
  __syncthreads();

  int cur = 0;
  for (int kt = kt0; kt < kt_end; kt += 64) {
    bool has_next = (kt + 64) < kt_end;   // block-uniform

    // ---- Phase 1: QK^T for BOTH 32-kpos halves (32 indep MFMAs) ----
    f32x4 s[2][4][2];   // [h][f][{rows col, rows 16+col}]
    __builtin_amdgcn_s_setprio(1);
#pragma unroll
    for (int h = 0; h < 2; ++h) {
      bf16x8 a00 = *(const bf16x8*)&k_lds[cur][h * 32 + col][quad * 8];
      bf16x8 a01 = *(const bf16x8*)&k_lds[cur][h * 32 + col][32 + quad * 8];
      bf16x8 a10 = *(const bf16x8*)&k_lds[cur][h * 32 + 16 + col][quad * 8];
      bf16x8 a11 = *(const bf16x8*)&k_lds[cur][h * 32 + 16 + col][32 + quad * 8];
#pragma unroll
      for (int f = 0; f < 4; ++f) {
        s[h][f][0] = __builtin_amdgcn_mfma_f32_16x16x32_bf16(a00, bq[f][0], Z, 0, 0, 0);
        s[h][f][1] = __builtin_amdgcn_mfma_f32_16x16x32_bf16(a10, bq[f][0], Z, 0, 0, 0);
        s[h][f][0] = __builtin_amdgcn_mfma_f32_16x16x32_bf16(a01, bq[f][1], s[h][f][0], 0, 0, 0);
        s[h][f][1] = __builtin_amdgcn_mfma_f32_16x16x32_bf16(a11, bq[f][1], s[h][f][1], 0, 0, 0);
      }
    }
    __builtin_amdgcn_s_setprio(0);

    // ---- Phase 2: issue next tile's global loads (land under exp/PV) ----
    uint4 nk0, nk1, nv0, nv1;
    if (has_next) {
      const uint4* ksrc = (const uint4*)(kp + (size_t)(kt + 64) * D_);
      nk0 = ksrc[tid];
      nk1 = ksrc[tid + 256];
      const uint4* vsrc = (const uint4*)(vp + (size_t)vrow * L_ + (kt + 64));
      nv0 = vsrc[vchunk * 2];
      nv1 = vsrc[vchunk * 2 + 1];
    }

    // ---- Phase 3: per half: exp/pack (VALU) + psum (MFMA) + PV (MFMA) ----
#pragma unroll
    for (int h = 0; h < 2; ++h) {
      bf16x8 pb[4];
#pragma unroll
      for (int f = 0; f < 4; ++f) {
        float pe0[4], pe1[4];
#pragma unroll
        for (int r = 0; r < 4; ++r) {
          pe0[r] = fastexp2(s[h][f][0][r]);
          pe1[r] = fastexp2(s[h][f][1][r]);
        }
        // B-frag IS our own values under the kpos permutation.
        union { unsigned u[4]; bf16x8 v8; } pc;
        pc.u[0] = __builtin_amdgcn_perm(fbits(pe0[1]), fbits(pe0[0]), 0x07060302u);
        pc.u[1] = __builtin_amdgcn_perm(fbits(pe0[3]), fbits(pe0[2]), 0x07060302u);
        pc.u[2] = __builtin_amdgcn_perm(fbits(pe1[1]), fbits(pe1[0]), 0x07060302u);
        pc.u[3] = __builtin_amdgcn_perm(fbits(pe1[3]), fbits(pe1[2]), 0x07060302u);
        pb[f] = pc.v8;
      }
      // psum on the matrix pipe: row-sum of P (permutation-invariant)
#pragma unroll
      for (int f = 0; f < 4; ++f)
        pacc[f] = __builtin_amdgcn_mfma_f32_16x16x32_bf16(ones, pb[f], pacc[f], 0, 0, 0);
#pragma unroll
      for (int t = 0; t < 4; ++t) {
        // ONE b128 read feeds FOUR MFMAs (V pre-permuted at store time)
        bf16x8 av = *(const bf16x8*)&v_lds[cur][t * 16 + col][h * 32 + quad * 8];
#pragma unroll
        for (int f = 0; f < 4; ++f)
          oacc[f][t] = __builtin_amdgcn_mfma_f32_16x16x32_bf16(av, pb[f], oacc[f][t], 0, 0, 0);
      }
    }

    if (has_next) {
      int nb = cur ^ 1;
      *(uint4*)&k_lds[nb][tid >> 3][(tid & 7) * 8] = nk0;
      *(uint4*)&k_lds[nb][32 + (tid >> 3)][(tid & 7) * 8] = nk1;
      ushort* vb = &v_lds[nb][vrow][vwoff];
      *(uint2*)(vb + 0)  = make_uint2(nv0.x, nv0.y);
      *(uint2*)(vb + 8)  = make_uint2(nv0.z, nv0.w);
      *(uint2*)(vb + 16) = make_uint2(nv1.x, nv1.y);
      *(uint2*)(vb + 24) = make_uint2(nv1.z, nv1.w);
      __syncthreads();
      cur = nb;
    }
  }

  ushort* po = split ? p1 : p0;
#pragma unroll
  for (int f = 0; f < 4; ++f) {
    for (int t = 0; t < 4; ++t) {
      ushort ok[4];
      for (int r = 0; r < 4; ++r) ok[r] = f2bf(oacc[f][t][r]);   // unnormalized
      ushort* dst = po + ((size_t)bh * L_ + qrow0 + f * 16 + col) * D_ + t * 16 + quad * 4;
      *(ushort4*)dst = make_ushort4(ok[0], ok[1], ok[2], ok[3]);
    }
    if (quad == 0)
      psumbuf[split * (16 * L_) + bh * L_ + qrow0 + f * 16 + col] = pacc[f][0];
  }
}

// ---------------------------------------------------------------------------
// 3b) Combine (FALLBACK path only): oat = (U0+U1)/(P0+P1), in-place over p0.
// ---------------------------------------------------------------------------
__global__ __launch_bounds__(256) void comb_kernel(ushort* __restrict__ p0,      // in/out (oat)
                                                   const ushort* __restrict__ p1,
                                                   const float* __restrict__ ps) {
  int idx = blockIdx.x * 256 + threadIdx.x;    // 524,288 uint4s = 16*4096*64 bf16
  int row = idx >> 3;                          // bh*4096 + qrow (8 elems/row-chunk)
  float inv = 1.0f / (ps[row] + ps[16 * L_ + row]);
  union { uint4 u; ushort s[8]; } ua, ub, o;
  ua.u = ((const uint4*)p0)[idx];
  ub.u = ((const uint4*)p1)[idx];
#pragma unroll
  for (int e = 0; e < 8; ++e)
    o.s[e] = f2bf((bf2f(ua.s[e]) + bf2f(ub.s[e])) * inv);
  ((uint4*)p0)[idx] = o.u;
}

// ---------------------------------------------------------------------------
// 4) Proj GEMM + residual (MFMA), per-block LDS combine (R11/R12-proven).
//    FUSED=true: stage combined A-tile once per block; FUSED=false: classic.
// ---------------------------------------------------------------------------
template<bool FUSED>
__global__ __launch_bounds__(256) void proj_kernel(const ushort* __restrict__ p0,
                                                   const ushort* __restrict__ p1,
                                                   const float* __restrict__ ps,
                                                   const ushort* __restrict__ pw,
                                                   const float* __restrict__ pb,
                                                   const float* __restrict__ x,
                                                   float* __restrict__ out) {
  __shared__ __align__(16) ushort a_lds[32][264];   // 32 l x 256 ch, +8 pad

  int tid  = threadIdx.x;
  int w    = tid >> 6, lane = tid & 63;
  int quad = lane >> 4, col = lane & 15;
  int bid  = (int)blockIdx.x;                 // 1024 blocks
  int oct  = (bid & 1) * 4 + w;               // 8 oc-tiles of 32
  int lt   = (bid >> 1) & 127;                // 128 l-tiles of 32
  int b    = bid >> 8;
  int l0 = lt * 32, oc0 = oct * 32;

  if (FUSED) {
    // stage combined A-tile: thread -> (l_local = tid&31, chunk = tid>>5)
    int ll = tid & 31, chunk = tid >> 5;      // chunk 0..7 -> 32 channels
    int hh = chunk >> 1, d0 = (chunk & 1) * 32;
    size_t row = (size_t)(b * NH_ + hh) * L_ + l0 + ll;
    float inv = 1.0f / (ps[row] + ps[16 * L_ + row]);
    const uint4* s0 = (const uint4*)(p0 + row * D_ + d0);
    const uint4* s1 = (const uint4*)(p1 + row * D_ + d0);
    union { uint4 u[4]; ushort s[32]; } ua, ub, o;
#pragma unroll
    for (int i = 0; i < 4; ++i) { ua.u[i] = s0[i]; ub.u[i] = s1[i]; }
#pragma unroll
    for (int e = 0; e < 32; ++e)
      o.s[e] = f2bf((bf2f(ua.s[e]) + bf2f(ub.s[e])) * inv);
#pragma unroll
    for (int i = 0; i < 4; ++i)
      *(uint4*)&a_lds[ll][chunk * 32 + i * 8] = o.u[i];
    __syncthreads();
  }

  f32x4 acc[2][2];
  for (int i = 0; i < 2; ++i) for (int j = 0; j < 2; ++j)
    acc[i][j] = (f32x4){0.f, 0.f, 0.f, 0.f};

#pragma unroll
  for (int k0 = 0; k0 < C_; k0 += 32) {
    int hh = k0 >> 6, dk = k0 & 63;
    bf16x8 a[2], bb[2];
#pragma unroll
    for (int i = 0; i < 2; ++i) {
      if (FUSED) {
        a[i] = *(const bf16x8*)&a_lds[i * 16 + col][k0 + quad * 8];
      } else {
        a[i] = *(const bf16x8*)(p0 + ((size_t)(b * NH_ + hh) * L_ + l0 + i * 16 + col) * D_ + dk + quad * 8);
      }
    }
#pragma unroll
    for (int j = 0; j < 2; ++j)
      bb[j] = *(const bf16x8*)(pw + (size_t)(oc0 + j * 16 + col) * C_ + k0 + quad * 8);
#pragma unroll
    for (int i = 0; i < 2; ++i)
#pragma unroll
      for (int j = 0; j < 2; ++j)
        acc[i][j] = __builtin_amdgcn_mfma_f32_16x16x32_bf16(a[i], bb[j], acc[i][j], 0, 0, 0);
  }

#pragma unroll
  for (int j = 0; j < 2; ++j) {
    int oc = oc0 + j * 16 + col;
    float bias = pb[oc];
#pragma unroll
    for (int i = 0; i < 2; ++i) {
      int l = l0 + i * 16 + quad * 4;
      size_t off = ((size_t)b * C_ + oc) * L_ + l;
      float4 xv = *(const float4*)(x + off);
      float4 ov = make_float4(acc[i][j][0] + bias + xv.x,
                              acc[i][j][1] + bias + xv.y,
                              acc[i][j][2] + bias + xv.z,
                              acc[i][j][3] + bias + xv.w);
      *(float4*)(out + off) = ov;
    }
  }
}

// ---------------------------------------------------------------------------
extern "C" void kernel_launch(void* const* d_in, const int* in_sizes, int n_in,
                              void* d_out, int out_size, void* d_ws, size_t ws_size,
                              hipStream_t stream) {
  const float* x      = (const float*)d_in[0];
  const float* gn_w   = (const float*)d_in[1];
  const float* gn_b   = (const float*)d_in[2];
  const float* qkv_w  = (const float*)d_in[3];
  const float* qkv_b  = (const float*)d_in[4];
  const float* proj_w = (const float*)d_in[5];
  const float* proj_b = (const float*)d_in[6];
  float* out = (float*)d_out;     // OUTPUT IS F32

  const size_t TEN = (size_t)B_ * C_ * L_;   // 4,194,304 elements
  // ws base layout (34.1 MB): q | k | v | oat | wq | wp | [p1 | psum if room]
  // d_out (16.8 MB): st2 f32 4KB at +8.4MB (dead before out is written);
  //                  fallback also places p1/psum here.
  ushort* ws  = (ushort*)d_ws;
  ushort* q   = ws;                 // (B, nh, L, d) bf16 (pre-scaled)
  ushort* k   = ws + TEN;           // (B, nh, L, d) bf16
  ushort* v   = ws + 2 * TEN;       // (B, nh, d, L) bf16
  ushort* oat = ws + 3 * TEN;       // (B, nh, L, d) bf16 = partial-0
  ushort* wq  = ws + 4 * TEN;       // (768,256) bf16
  ushort* wp  = wq + 768 * 256;     // (256,256) bf16
  ushort* wend = wp + 256 * 256;    // end of base layout
  float*  st2 = (float*)((ushort*)d_out + TEN);  // 1024 f32 GN partials (pre-attn)

  const size_t base_bytes  = (size_t)(wend - ws) * 2;
  const size_t need_fused  = base_bytes + TEN * 2 /*p1*/ + (size_t)2 * 16 * L_ * 4 /*psum*/;
  const bool   fused       = ws_size >= need_fused;   // true on this harness (R9 evidence)

  pre_kernel <<<768,       256, 0, stream>>>(x, qkv_w, proj_w, wq, wp, st2);
  qkv_kernel <<<512,       256, 0, stream>>>(x, st2, gn_w, gn_b, wq, qkv_b, q, k, v);

  if (fused) {
    ushort* p1w = wend;                    // partial-1 in ws
    float*  psw = (float*)(wend + TEN);    // psum[2][16][4096] in ws
    attn_kernel<<<512, 256, 0, stream>>>(q, k, v, oat, p1w, psw);
    proj_kernel<true><<<1024, 256, 0, stream>>>(oat, p1w, psw, wp, proj_b, x, out);
  } else {
    // fallback: p1 + psum live in d_out (st2 is dead after qkv)
    ushort* p1d = (ushort*)d_out + TEN;
    float*  psb = (float*)d_out;
    attn_kernel<<<512, 256, 0, stream>>>(q, k, v, oat, p1d, psb);
    comb_kernel<<<2048, 256, 0, stream>>>(oat, p1d, psb);
    proj_kernel<false><<<1024, 256, 0, stream>>>(oat, oat, psb, wp, proj_b, x, out);
  }
}